// Round 5
// baseline (343.803 us; speedup 1.0000x reference)
//
#include <hip/hip_runtime.h>
#include <hip/hip_bf16.h>

#define NT 64
#define DIM 128

typedef __attribute__((ext_vector_type(8))) short short8;
typedef __attribute__((ext_vector_type(4))) short short4v;
typedef __attribute__((ext_vector_type(8))) __bf16 bf16x8;
typedef __attribute__((ext_vector_type(4))) float floatx4;
typedef __attribute__((ext_vector_type(4))) unsigned uintx4;

#define MFMA(a,b,c) __builtin_amdgcn_mfma_f32_16x16x32_bf16(a,b,c,0,0,0)
// flat-index XOR swizzle (bijective, 16B granules)
#define SWZ(idx, row) ((idx) ^ (((row)&7)<<3))

__device__ __forceinline__ short bfbits(float f) {
  return __builtin_bit_cast(short, (__bf16)f);
}
__device__ __forceinline__ unsigned pk2(float lo, float hi) {
  return (unsigned)(unsigned short)__builtin_bit_cast(unsigned short, (__bf16)lo)
       | ((unsigned)(unsigned short)__builtin_bit_cast(unsigned short, (__bf16)hi) << 16);
}
__device__ __forceinline__ bf16x8 frag_bf(const short* __restrict__ p) {
  return __builtin_bit_cast(bf16x8, *(const short8*)p);
}
__device__ __forceinline__ short8 pack8(float4 a, float4 b) {
  short8 v;
  v[0]=bfbits(a.x); v[1]=bfbits(a.y); v[2]=bfbits(a.z); v[3]=bfbits(a.w);
  v[4]=bfbits(b.x); v[5]=bfbits(b.y); v[6]=bfbits(b.z); v[7]=bfbits(b.w);
  return v;
}

// ---------------- prep: CPB MLP + bias packing (S^T order) + weight bf16 ----
// bias_packed[f], f = (((h*4+mk)*4+qt)*64+lane)*4+i :
//   value = 16*sigmoid(logits at (q = qt*16+(lane&15), k = mk*16+((lane>>4)&3)*4+i))
__global__ void prep_kernel(const float* __restrict__ table,
                            const float* __restrict__ w1,
                            const float* __restrict__ b1,
                            const float* __restrict__ w2,
                            const int*   __restrict__ idx,
                            const float* __restrict__ q_w,
                            const float* __restrict__ kv_w,
                            const float* __restrict__ proj_w,
                            float* __restrict__ bias_packed,
                            short* __restrict__ wbf) {
  int t = threadIdx.x;
  if (blockIdx.x == 0) {
    __shared__ float logits[225][4];
    if (t < 225) {
      float t0 = table[2*t], t1 = table[2*t+1];
      float a0=0.f, a1=0.f, a2=0.f, a3=0.f;
      for (int j = 0; j < 512; ++j) {
        float h = fmaxf(0.f, t0 * w1[2*j] + t1 * w1[2*j+1] + b1[j]);
        a0 += h * w2[j];
        a1 += h * w2[512 + j];
        a2 += h * w2[1024 + j];
        a3 += h * w2[1536 + j];
      }
      logits[t][0]=a0; logits[t][1]=a1; logits[t][2]=a2; logits[t][3]=a3;
    }
    __syncthreads();
    for (int f = t; f < 16384; f += 256) {
      int i    = f & 3;
      int lane = (f >> 2) & 63;
      int qt   = (f >> 8) & 3;
      int mk   = (f >> 10) & 3;
      int h    = f >> 12;
      int q = qt*16 + (lane & 15);
      int k = mk*16 + ((lane >> 4) & 3)*4 + i;
      int p = idx[q*64 + k];
      float v = logits[p][h];
      bias_packed[f] = 16.f / (1.f + __expf(-v));
    }
  } else {
    int gidx = (blockIdx.x - 1) * 4096 + t * 16;
    const float* src; int off;
    if (gidx < 16384)      { src = q_w;    off = gidx; }
    else if (gidx < 49152) { src = kv_w;   off = gidx - 16384; }
    else                   { src = proj_w; off = gidx - 49152; }
    const float4* s = (const float4*)(src + off);
    short* dst = wbf + gidx;
#pragma unroll
    for (int i = 0; i < 2; ++i)
      *(short8*)(dst + i*8) = pack8(s[2*i], s[2*i+1]);
  }
}

// ---------------- main fused kernel: one block (512 thr) per window --------
// wave = (head h, token-half s). Swapped-operand MFMA; qn & P in registers;
// LDS 48KB = xb/vT 16K + cb/outp 16K + kn 16K -> 3 blocks/CU.
__global__ __launch_bounds__(512, 6)
void swin_ctx_attn_kernel(const float* __restrict__ x, const float* __restrict__ ctx,
                          const float* __restrict__ mask,
                          const short* __restrict__ wq, const float* __restrict__ q_b,
                          const short* __restrict__ wkv, const float* __restrict__ v_b,
                          const float* __restrict__ logit_scale,
                          const short* __restrict__ wproj, const float* __restrict__ proj_b,
                          const float* __restrict__ bias_p,
                          float* __restrict__ out) {
  __shared__ short lds[24576] __attribute__((aligned(16)));  // 48 KB
  const int tid  = threadIdx.x;
  const int lane = tid & 63;
  const int wv   = tid >> 6;      // 0..7
  const int h    = wv >> 1;       // head
  const int s    = wv & 1;        // token-half (q rows s*32..+32)
  const int b    = blockIdx.x;
  const int lr   = lane & 15;
  const int lg   = lane >> 4;

  short* xb   = lds;              // [64][128] swz : x  -> later vT [128][64]
  short* cb   = lds + 8192;       // [64][128] swz : ctx -> later outp [64][128]
  short* kn   = lds + 16384;      // [4][64][32] swz
  short* vT   = xb;
  short* outp = cb;
  short* knh  = kn + h*2048;

  const float* xw = x   + (size_t)b*(NT*DIM);
  const float* cw = ctx + (size_t)b*(NT*DIM);

  // ---- stage x + ctx together ----
  {
    const int sr = tid >> 3, sc0 = (tid & 7) * 16;
    const float4* xs = (const float4*)(xw + sr*DIM + sc0);
    const float4* cs = (const float4*)(cw + sr*DIM + sc0);
    float4 xr[4], cr[4];
#pragma unroll
    for (int i = 0; i < 4; ++i) xr[i] = xs[i];
#pragma unroll
    for (int i = 0; i < 4; ++i) cr[i] = cs[i];
#pragma unroll
    for (int i = 0; i < 2; ++i)
      *(short8*)(xb + SWZ(sr*128 + sc0 + i*8, sr)) = pack8(xr[2*i], xr[2*i+1]);
#pragma unroll
    for (int i = 0; i < 2; ++i)
      *(short8*)(cb + SWZ(sr*128 + sc0 + i*8, sr)) = pack8(cr[2*i], cr[2*i+1]);
  }
  __syncthreads();  // B1: x + ctx staged

  // shuffle constants for register-transposes
  const int sA = ((lane & 16) << 1) | (lane & 15);   // src lane for j<4
  const int sB = sA + 16;                            // src lane for j>=4
  const unsigned selp = (lane & 32) ? 0x07060302u : 0x05040100u;

  // ---- Q^T = q_w @ x^T (C: [ch][tok-own]) ----
  bf16x8 qB[2];   // S^T B-frags, built in-register
  float scl = __expf(fminf(logit_scale[h], 4.605170185988091f));  // log(100)
  {
    floatx4 aq[2][2] = {};
    for (int ks = 0; ks < 4; ++ks) {
      bf16x8 xf[2], wf[2];
#pragma unroll
      for (int n = 0; n < 2; ++n) {
        int tok = (2*s + n)*16 + lr;
        xf[n] = frag_bf(xb + SWZ(tok*128 + ks*32 + lg*8, tok));
      }
#pragma unroll
      for (int mc = 0; mc < 2; ++mc)
        wf[mc] = frag_bf(wq + (h*32 + mc*16 + lr)*DIM + ks*32 + lg*8);
#pragma unroll
      for (int mc = 0; mc < 2; ++mc)
#pragma unroll
        for (int n = 0; n < 2; ++n)
          aq[mc][n] = MFMA(wf[mc], xf[n], aq[mc][n]);
    }
    floatx4 qb4[2];
#pragma unroll
    for (int mc = 0; mc < 2; ++mc)
      qb4[mc] = *(const floatx4*)(q_b + h*32 + mc*16 + lg*4);
#pragma unroll
    for (int n = 0; n < 2; ++n) {
      float ss = 0.f;
#pragma unroll
      for (int mc = 0; mc < 2; ++mc)
#pragma unroll
        for (int i = 0; i < 4; ++i) {
          aq[mc][n][i] += qb4[mc][i];
          ss += aq[mc][n][i]*aq[mc][n][i];
        }
      ss += __shfl_xor(ss, 16, 64);
      ss += __shfl_xor(ss, 32, 64);
      float sc = scl / fmaxf(sqrtf(ss), 1e-12f);   // fold logit scale into Q
#pragma unroll
      for (int mc = 0; mc < 2; ++mc)
#pragma unroll
        for (int i = 0; i < 4; ++i) aq[mc][n][i] *= sc;
      // build qB[n]: element j = Qn[q=(2s+n)*16+lr][ch=lg*8+j]
      unsigned pq[4], w[8];
#pragma unroll
      for (int i = 0; i < 4; ++i) pq[i] = pk2(aq[0][n][i], aq[1][n][i]);
#pragma unroll
      for (int j = 0; j < 8; ++j) w[j] = __shfl(pq[j & 3], (j < 4) ? sA : sB, 64);
      uintx4 u;
#pragma unroll
      for (int t = 0; t < 4; ++t) u[t] = __builtin_amdgcn_perm(w[2*t+1], w[2*t], selp);
      qB[n] = __builtin_bit_cast(bf16x8, u);
    }
  }

  // ---- K^T and V (shared ctx frags) ----
  floatx4 ak[2][2] = {}, av[2][2] = {};
  for (int ks = 0; ks < 4; ++ks) {
    bf16x8 cf[2], wkf[2], wvf[2];
#pragma unroll
    for (int r = 0; r < 2; ++r) {
      int tok = (2*s + r)*16 + lr;
      cf[r] = frag_bf(cb + SWZ(tok*128 + ks*32 + lg*8, tok));
    }
#pragma unroll
    for (int mc = 0; mc < 2; ++mc) {
      wkf[mc] = frag_bf(wkv + (h*32 + mc*16 + lr)*DIM + ks*32 + lg*8);
      wvf[mc] = frag_bf(wkv + (DIM + h*32 + mc*16 + lr)*DIM + ks*32 + lg*8);
    }
#pragma unroll
    for (int mc = 0; mc < 2; ++mc)
#pragma unroll
      for (int n = 0; n < 2; ++n) {
        ak[mc][n] = MFMA(wkf[mc], cf[n], ak[mc][n]);   // K^T [ch][tok]
        av[mc][n] = MFMA(cf[mc], wvf[n], av[mc][n]);   // V   [tok][ch]
      }
  }
  // K l2norm (per token col)
#pragma unroll
  for (int n = 0; n < 2; ++n) {
    float ss = 0.f;
#pragma unroll
    for (int mc = 0; mc < 2; ++mc)
#pragma unroll
      for (int i = 0; i < 4; ++i) ss += ak[mc][n][i]*ak[mc][n][i];
    ss += __shfl_xor(ss, 16, 64);
    ss += __shfl_xor(ss, 32, 64);
    float sc = 1.0f / fmaxf(sqrtf(ss), 1e-12f);
#pragma unroll
    for (int mc = 0; mc < 2; ++mc)
#pragma unroll
      for (int i = 0; i < 4; ++i) ak[mc][n][i] *= sc;
  }
  // kn[tok][ch] writes (own region, pre-B2 ok)
#pragma unroll
  for (int mc = 0; mc < 2; ++mc)
#pragma unroll
    for (int n = 0; n < 2; ++n) {
      int tok = (2*s + n)*16 + lr;
      short4v t4;
#pragma unroll
      for (int i = 0; i < 4; ++i) t4[i] = bfbits(ak[mc][n][i]);
      *(short4v*)(knh + SWZ(tok*32 + mc*16 + lg*4, tok)) = t4;
    }
  __syncthreads();  // B2: all xb (Q) + cb (K/V) reads done

  // vT[chG][tok] writes (overlays xb)
  {
    float vb0 = v_b[h*32 + lr], vb1 = v_b[h*32 + 16 + lr];
#pragma unroll
    for (int m = 0; m < 2; ++m)
#pragma unroll
      for (int n = 0; n < 2; ++n) {
        int chG = h*32 + n*16 + lr;
        float vb = n ? vb1 : vb0;
        short4v t4;
#pragma unroll
        for (int i = 0; i < 4; ++i) t4[i] = bfbits(av[m][n][i] + vb);
        *(short4v*)(vT + SWZ(chG*64 + s*32 + m*16 + lg*4, chG)) = t4;
      }
  }
  __syncthreads();  // B3: kn + vT ready

  // ---- S^T = K @ Qn^T : [k-tok 64][q-own 32] ----
  floatx4 st[4][2] = {};
  {
    bf16x8 kf[4];
#pragma unroll
    for (int mk = 0; mk < 4; ++mk) {
      int tok = mk*16 + lr;
      kf[mk] = frag_bf(knh + SWZ(tok*32 + lg*8, tok));
    }
#pragma unroll
    for (int mk = 0; mk < 4; ++mk)
#pragma unroll
      for (int n = 0; n < 2; ++n)
        st[mk][n] = MFMA(kf[mk], qB[n], st[mk][n]);
  }

  // ---- +bias +mask, softmax over k (lane-local 16 + 2 shfl) ----
  float rinv[2];
  {
    int wimg = b & 63;
#pragma unroll
    for (int n = 0; n < 2; ++n) {
      int qcol = (2*s + n)*16 + lr;
#pragma unroll
      for (int mk = 0; mk < 4; ++mk) {
        floatx4 b4 = ((const floatx4*)bias_p)[((h*4 + mk)*4 + (2*s + n))*64 + lane];
        floatx4 m4 = *(const floatx4*)(mask + ((size_t)wimg*64 + qcol)*64 + mk*16 + lg*4);
#pragma unroll
        for (int i = 0; i < 4; ++i) st[mk][n][i] += b4[i] + m4[i];
      }
      float mx = st[0][n][0];
#pragma unroll
      for (int mk = 0; mk < 4; ++mk)
#pragma unroll
        for (int i = 0; i < 4; ++i) mx = fmaxf(mx, st[mk][n][i]);
      mx = fmaxf(mx, __shfl_xor(mx, 16, 64));
      mx = fmaxf(mx, __shfl_xor(mx, 32, 64));
      float sum = 0.f;
#pragma unroll
      for (int mk = 0; mk < 4; ++mk)
#pragma unroll
        for (int i = 0; i < 4; ++i) {
          st[mk][n][i] = __expf(st[mk][n][i] - mx);
          sum += st[mk][n][i];
        }
      sum += __shfl_xor(sum, 16, 64);
      sum += __shfl_xor(sum, 32, 64);
      rinv[n] = 1.0f / sum;   // folded into O^T rescale
    }
  }

  // ---- build P B-frags in-register, PV: O^T = V^T @ P^T ----
  floatx4 ot[2][2] = {};
#pragma unroll
  for (int kk = 0; kk < 2; ++kk) {
    bf16x8 pB[2];
#pragma unroll
    for (int n = 0; n < 2; ++n) {
      unsigned pp[4], w[8];
#pragma unroll
      for (int i = 0; i < 4; ++i) pp[i] = pk2(st[2*kk][n][i], st[2*kk+1][n][i]);
#pragma unroll
      for (int j = 0; j < 8; ++j) w[j] = __shfl(pp[j & 3], (j < 4) ? sA : sB, 64);
      uintx4 u;
#pragma unroll
      for (int t = 0; t < 4; ++t) u[t] = __builtin_amdgcn_perm(w[2*t+1], w[2*t], selp);
      pB[n] = __builtin_bit_cast(bf16x8, u);
    }
    bf16x8 vf[2];
#pragma unroll
    for (int mo = 0; mo < 2; ++mo) {
      int chG = h*32 + mo*16 + lr;
      vf[mo] = frag_bf(vT + SWZ(chG*64 + kk*32 + lg*8, chG));
    }
#pragma unroll
    for (int mo = 0; mo < 2; ++mo)
#pragma unroll
      for (int n = 0; n < 2; ++n)
        ot[mo][n] = MFMA(vf[mo], pB[n], ot[mo][n]);
  }

  // ---- rescale by 1/sum, write outp[tok][ch] (overlays cb) ----
#pragma unroll
  for (int mo = 0; mo < 2; ++mo)
#pragma unroll
    for (int n = 0; n < 2; ++n) {
      int tok = (2*s + n)*16 + lr;
      short4v t4;
#pragma unroll
      for (int i = 0; i < 4; ++i) t4[i] = bfbits(ot[mo][n][i] * rinv[n]);
      *(short4v*)(outp + SWZ(tok*128 + h*32 + mo*16 + lg*4, tok)) = t4;
    }
  __syncthreads();  // B4: outp ready

  // ---- out = outp @ proj_w.T + proj_b ----
  {
    floatx4 ap[2][2] = {};
    for (int ks = 0; ks < 4; ++ks) {
      bf16x8 of[2], wpf[2];
#pragma unroll
      for (int m = 0; m < 2; ++m) {
        int tok = s*32 + m*16 + lr;
        of[m] = frag_bf(outp + SWZ(tok*128 + ks*32 + lg*8, tok));
      }
#pragma unroll
      for (int n = 0; n < 2; ++n)
        wpf[n] = frag_bf(wproj + (h*32 + n*16 + lr)*DIM + ks*32 + lg*8);
#pragma unroll
      for (int m = 0; m < 2; ++m)
#pragma unroll
        for (int n = 0; n < 2; ++n)
          ap[m][n] = MFMA(of[m], wpf[n], ap[m][n]);
    }
    float pb0 = proj_b[h*32 + lr], pb1 = proj_b[h*32 + 16 + lr];
    float* op = out + (size_t)b * (NT*DIM);
#pragma unroll
    for (int m = 0; m < 2; ++m)
#pragma unroll
      for (int n = 0; n < 2; ++n) {
        float pb = n ? pb1 : pb0;
#pragma unroll
        for (int i = 0; i < 4; ++i)
          op[(s*32 + m*16 + lg*4 + i)*DIM + h*32 + n*16 + lr] = ap[m][n][i] + pb;
      }
  }
}

extern "C" void kernel_launch(void* const* d_in, const int* in_sizes, int n_in,
                              void* d_out, int out_size, void* d_ws, size_t ws_size,
                              hipStream_t stream) {
  const float* x     = (const float*)d_in[0];
  const float* ctx   = (const float*)d_in[1];
  const float* mask  = (const float*)d_in[2];
  const float* q_w   = (const float*)d_in[3];
  const float* q_b   = (const float*)d_in[4];
  const float* kv_w  = (const float*)d_in[5];
  const float* v_b   = (const float*)d_in[6];
  const float* ls    = (const float*)d_in[7];
  const float* w1    = (const float*)d_in[8];
  const float* b1    = (const float*)d_in[9];
  const float* w2    = (const float*)d_in[10];
  const float* pw    = (const float*)d_in[11];
  const float* pb    = (const float*)d_in[12];
  const float* table = (const float*)d_in[13];
  const int*   idx   = (const int*)d_in[14];

  float* bias_p = (float*)d_ws;                       // 16384 f32 = 64 KB
  short* wbf    = (short*)((char*)d_ws + 65536);      // 65536 bf16 = 128 KB
  short* wq     = wbf;
  short* wkv    = wbf + 16384;
  short* wproj  = wbf + 49152;
  int B = in_sizes[0] / (NT * DIM);

  prep_kernel<<<17, 256, 0, stream>>>(table, w1, b1, w2, idx, q_w, kv_w, pw,
                                      bias_p, wbf);
  swin_ctx_attn_kernel<<<B, 512, 0, stream>>>(x, ctx, mask, wq, q_b, wkv, v_b,
                                              ls, wproj, pb, bias_p, (float*)d_out);
}

// Round 6
// 272.477 us; speedup vs baseline: 1.2618x; 1.2618x over previous
//
#include <hip/hip_runtime.h>
#include <hip/hip_bf16.h>

#define NT 64
#define DIM 128

typedef __attribute__((ext_vector_type(8))) short short8;
typedef __attribute__((ext_vector_type(4))) short short4v;
typedef __attribute__((ext_vector_type(8))) __bf16 bf16x8;
typedef __attribute__((ext_vector_type(4))) float floatx4;
typedef __attribute__((ext_vector_type(4))) unsigned uintx4;

#define MFMA(a,b,c) __builtin_amdgcn_mfma_f32_16x16x32_bf16(a,b,c,0,0,0)
// flat-index XOR swizzle (bijective, 16B granules)
#define SWZ(idx, row) ((idx) ^ (((row)&7)<<3))

__device__ __forceinline__ short bfbits(float f) {
  return __builtin_bit_cast(short, (__bf16)f);
}
__device__ __forceinline__ unsigned pk2(float lo, float hi) {
  return (unsigned)(unsigned short)__builtin_bit_cast(unsigned short, (__bf16)lo)
       | ((unsigned)(unsigned short)__builtin_bit_cast(unsigned short, (__bf16)hi) << 16);
}
__device__ __forceinline__ bf16x8 frag_bf(const short* __restrict__ p) {
  return __builtin_bit_cast(bf16x8, *(const short8*)p);
}
__device__ __forceinline__ short8 pack8(float4 a, float4 b) {
  short8 v;
  v[0]=bfbits(a.x); v[1]=bfbits(a.y); v[2]=bfbits(a.z); v[3]=bfbits(a.w);
  v[4]=bfbits(b.x); v[5]=bfbits(b.y); v[6]=bfbits(b.z); v[7]=bfbits(b.w);
  return v;
}

// ---------------- prep: CPB MLP + bias packing (S^T order) + weight bf16 ----
__global__ void prep_kernel(const float* __restrict__ table,
                            const float* __restrict__ w1,
                            const float* __restrict__ b1,
                            const float* __restrict__ w2,
                            const int*   __restrict__ idx,
                            const float* __restrict__ q_w,
                            const float* __restrict__ kv_w,
                            const float* __restrict__ proj_w,
                            float* __restrict__ bias_packed,
                            short* __restrict__ wbf) {
  int t = threadIdx.x;
  if (blockIdx.x == 0) {
    __shared__ float logits[225][4];
    if (t < 225) {
      float t0 = table[2*t], t1 = table[2*t+1];
      float a0=0.f, a1=0.f, a2=0.f, a3=0.f;
      for (int j = 0; j < 512; ++j) {
        float h = fmaxf(0.f, t0 * w1[2*j] + t1 * w1[2*j+1] + b1[j]);
        a0 += h * w2[j];
        a1 += h * w2[512 + j];
        a2 += h * w2[1024 + j];
        a3 += h * w2[1536 + j];
      }
      logits[t][0]=a0; logits[t][1]=a1; logits[t][2]=a2; logits[t][3]=a3;
    }
    __syncthreads();
    for (int f = t; f < 16384; f += 256) {
      int i    = f & 3;
      int lane = (f >> 2) & 63;
      int qt   = (f >> 8) & 3;
      int mk   = (f >> 10) & 3;
      int h    = f >> 12;
      int q = qt*16 + (lane & 15);
      int k = mk*16 + ((lane >> 4) & 3)*4 + i;
      int p = idx[q*64 + k];
      float v = logits[p][h];
      bias_packed[f] = 16.f / (1.f + __expf(-v));
    }
  } else {
    int gidx = (blockIdx.x - 1) * 4096 + t * 16;
    const float* src; int off;
    if (gidx < 16384)      { src = q_w;    off = gidx; }
    else if (gidx < 49152) { src = kv_w;   off = gidx - 16384; }
    else                   { src = proj_w; off = gidx - 49152; }
    const float4* s = (const float4*)(src + off);
    short* dst = wbf + gidx;
#pragma unroll
    for (int i = 0; i < 2; ++i)
      *(short8*)(dst + i*8) = pack8(s[2*i], s[2*i+1]);
  }
}

// ---------------- main fused kernel: one block (512 thr) per window --------
// wave = (head h, token-half s). Register-Q + S^T layout; split K/V passes
// and staged pB build keep peak VGPR < 85 (6 waves/EU, no spill).
// LDS 48KB = xb/vT 16K + cb/outp 16K + kn 16K -> 3 blocks/CU.
__global__ __launch_bounds__(512, 6)
void swin_ctx_attn_kernel(const float* __restrict__ x, const float* __restrict__ ctx,
                          const float* __restrict__ mask,
                          const short* __restrict__ wq, const float* __restrict__ q_b,
                          const short* __restrict__ wkv, const float* __restrict__ v_b,
                          const float* __restrict__ logit_scale,
                          const short* __restrict__ wproj, const float* __restrict__ proj_b,
                          const float* __restrict__ bias_p,
                          float* __restrict__ out) {
  __shared__ short lds[24576] __attribute__((aligned(16)));  // 48 KB
  const int tid  = threadIdx.x;
  const int lane = tid & 63;
  const int wv   = tid >> 6;      // 0..7
  const int h    = wv >> 1;       // head
  const int s    = wv & 1;        // token-half (q rows s*32..+32)
  const int b    = blockIdx.x;
  const int lr   = lane & 15;
  const int lg   = lane >> 4;

  short* xb   = lds;              // [64][128] swz : x  -> later vT [128][64]
  short* cb   = lds + 8192;       // [64][128] swz : ctx -> later outp [64][128]
  short* kn   = lds + 16384;      // [4][64][32] swz
  short* vT   = xb;
  short* outp = cb;
  short* knh  = kn + h*2048;

  const float* xw = x   + (size_t)b*(NT*DIM);
  const float* cw = ctx + (size_t)b*(NT*DIM);

  // ---- stage x + ctx together ----
  {
    const int sr = tid >> 3, sc0 = (tid & 7) * 16;
    const float4* xs = (const float4*)(xw + sr*DIM + sc0);
    const float4* cs = (const float4*)(cw + sr*DIM + sc0);
    float4 xr[4], cr[4];
#pragma unroll
    for (int i = 0; i < 4; ++i) xr[i] = xs[i];
#pragma unroll
    for (int i = 0; i < 4; ++i) cr[i] = cs[i];
#pragma unroll
    for (int i = 0; i < 2; ++i)
      *(short8*)(xb + SWZ(sr*128 + sc0 + i*8, sr)) = pack8(xr[2*i], xr[2*i+1]);
#pragma unroll
    for (int i = 0; i < 2; ++i)
      *(short8*)(cb + SWZ(sr*128 + sc0 + i*8, sr)) = pack8(cr[2*i], cr[2*i+1]);
  }
  __syncthreads();  // B1: x + ctx staged

  // shuffle constants for register-transposes
  const int sA = ((lane & 16) << 1) | (lane & 15);   // src lane for j<4
  const int sB = sA + 16;                            // src lane for j>=4
  const unsigned selp = (lane & 32) ? 0x07060302u : 0x05040100u;

  // ---- Q^T = q_w @ x^T ; l2norm*scl ; build S^T B-frags in registers ----
  bf16x8 qB[2];
  float scl = __expf(fminf(logit_scale[h], 4.605170185988091f));  // log(100)
  {
    floatx4 aq[2][2] = {};
    for (int ks = 0; ks < 4; ++ks) {
      bf16x8 xf[2], wf[2];
#pragma unroll
      for (int n = 0; n < 2; ++n) {
        int tok = (2*s + n)*16 + lr;
        xf[n] = frag_bf(xb + SWZ(tok*128 + ks*32 + lg*8, tok));
      }
#pragma unroll
      for (int mc = 0; mc < 2; ++mc)
        wf[mc] = frag_bf(wq + (h*32 + mc*16 + lr)*DIM + ks*32 + lg*8);
#pragma unroll
      for (int mc = 0; mc < 2; ++mc)
#pragma unroll
        for (int n = 0; n < 2; ++n)
          aq[mc][n] = MFMA(wf[mc], xf[n], aq[mc][n]);
    }
    floatx4 qb4[2];
#pragma unroll
    for (int mc = 0; mc < 2; ++mc)
      qb4[mc] = *(const floatx4*)(q_b + h*32 + mc*16 + lg*4);
#pragma unroll
    for (int n = 0; n < 2; ++n) {
      float ss = 0.f;
#pragma unroll
      for (int mc = 0; mc < 2; ++mc)
#pragma unroll
        for (int i = 0; i < 4; ++i) {
          aq[mc][n][i] += qb4[mc][i];
          ss += aq[mc][n][i]*aq[mc][n][i];
        }
      ss += __shfl_xor(ss, 16, 64);
      ss += __shfl_xor(ss, 32, 64);
      float sc = scl / fmaxf(sqrtf(ss), 1e-12f);
#pragma unroll
      for (int mc = 0; mc < 2; ++mc)
#pragma unroll
        for (int i = 0; i < 4; ++i) aq[mc][n][i] *= sc;
      unsigned pq[4], w[8];
#pragma unroll
      for (int i = 0; i < 4; ++i) pq[i] = pk2(aq[0][n][i], aq[1][n][i]);
#pragma unroll
      for (int j = 0; j < 8; ++j) w[j] = __shfl(pq[j & 3], (j < 4) ? sA : sB, 64);
      uintx4 u;
#pragma unroll
      for (int t = 0; t < 4; ++t) u[t] = __builtin_amdgcn_perm(w[2*t+1], w[2*t], selp);
      qB[n] = __builtin_bit_cast(bf16x8, u);
    }
  }

  // ---- K pass (only ak live) ----
  {
    floatx4 ak[2][2] = {};
    for (int ks = 0; ks < 4; ++ks) {
      bf16x8 cf[2], wkf[2];
#pragma unroll
      for (int r = 0; r < 2; ++r) {
        int tok = (2*s + r)*16 + lr;
        cf[r] = frag_bf(cb + SWZ(tok*128 + ks*32 + lg*8, tok));
      }
#pragma unroll
      for (int mc = 0; mc < 2; ++mc)
        wkf[mc] = frag_bf(wkv + (h*32 + mc*16 + lr)*DIM + ks*32 + lg*8);
#pragma unroll
      for (int mc = 0; mc < 2; ++mc)
#pragma unroll
        for (int n = 0; n < 2; ++n)
          ak[mc][n] = MFMA(wkf[mc], cf[n], ak[mc][n]);   // K^T [ch][tok]
    }
#pragma unroll
    for (int n = 0; n < 2; ++n) {
      float ss = 0.f;
#pragma unroll
      for (int mc = 0; mc < 2; ++mc)
#pragma unroll
        for (int i = 0; i < 4; ++i) ss += ak[mc][n][i]*ak[mc][n][i];
      ss += __shfl_xor(ss, 16, 64);
      ss += __shfl_xor(ss, 32, 64);
      float sc = 1.0f / fmaxf(sqrtf(ss), 1e-12f);
#pragma unroll
      for (int mc = 0; mc < 2; ++mc)
#pragma unroll
        for (int i = 0; i < 4; ++i) ak[mc][n][i] *= sc;
    }
    // kn[tok][ch] writes (own region, pre-B2 ok)
#pragma unroll
    for (int mc = 0; mc < 2; ++mc)
#pragma unroll
      for (int n = 0; n < 2; ++n) {
        int tok = (2*s + n)*16 + lr;
        short4v t4;
#pragma unroll
        for (int i = 0; i < 4; ++i) t4[i] = bfbits(ak[mc][n][i]);
        *(short4v*)(knh + SWZ(tok*32 + mc*16 + lg*4, tok)) = t4;
      }
  }
  __syncthreads();  // B2: all xb (Q) reads done -> vT may overlay xb

  // ---- V pass (only av live) ----
  {
    floatx4 av[2][2] = {};
    for (int ks = 0; ks < 4; ++ks) {
      bf16x8 cf[2], wvf[2];
#pragma unroll
      for (int r = 0; r < 2; ++r) {
        int tok = (2*s + r)*16 + lr;
        cf[r] = frag_bf(cb + SWZ(tok*128 + ks*32 + lg*8, tok));
      }
#pragma unroll
      for (int mc = 0; mc < 2; ++mc)
        wvf[mc] = frag_bf(wkv + (DIM + h*32 + mc*16 + lr)*DIM + ks*32 + lg*8);
#pragma unroll
      for (int mc = 0; mc < 2; ++mc)
#pragma unroll
        for (int n = 0; n < 2; ++n)
          av[mc][n] = MFMA(cf[mc], wvf[n], av[mc][n]);   // V [tok][ch]
    }
    float vb0 = v_b[h*32 + lr], vb1 = v_b[h*32 + 16 + lr];
#pragma unroll
    for (int m = 0; m < 2; ++m)
#pragma unroll
      for (int n = 0; n < 2; ++n) {
        int chG = h*32 + n*16 + lr;
        float vb = n ? vb1 : vb0;
        short4v t4;
#pragma unroll
        for (int i = 0; i < 4; ++i) t4[i] = bfbits(av[m][n][i] + vb);
        *(short4v*)(vT + SWZ(chG*64 + s*32 + m*16 + lg*4, chG)) = t4;
      }
  }
  __syncthreads();  // B3: kn + vT ready

  // ---- S^T = K @ Qn^T : [k-tok 64][q-own 32] (kf loaded per-mk) ----
  floatx4 st[4][2] = {};
#pragma unroll
  for (int mk = 0; mk < 4; ++mk) {
    int tok = mk*16 + lr;
    bf16x8 kf = frag_bf(knh + SWZ(tok*32 + lg*8, tok));
#pragma unroll
    for (int n = 0; n < 2; ++n)
      st[mk][n] = MFMA(kf, qB[n], st[mk][n]);
  }

  // ---- +bias +mask, softmax over k (lane-local 16 + 2 shfl) ----
  float rinv[2];
  {
    int wimg = b & 63;
#pragma unroll
    for (int n = 0; n < 2; ++n) {
      int qcol = (2*s + n)*16 + lr;
#pragma unroll
      for (int mk = 0; mk < 4; ++mk) {
        floatx4 b4 = ((const floatx4*)bias_p)[((h*4 + mk)*4 + (2*s + n))*64 + lane];
        floatx4 m4 = *(const floatx4*)(mask + ((size_t)wimg*64 + qcol)*64 + mk*16 + lg*4);
#pragma unroll
        for (int i = 0; i < 4; ++i) st[mk][n][i] += b4[i] + m4[i];
      }
      float mx = st[0][n][0];
#pragma unroll
      for (int mk = 0; mk < 4; ++mk)
#pragma unroll
        for (int i = 0; i < 4; ++i) mx = fmaxf(mx, st[mk][n][i]);
      mx = fmaxf(mx, __shfl_xor(mx, 16, 64));
      mx = fmaxf(mx, __shfl_xor(mx, 32, 64));
      float sum = 0.f;
#pragma unroll
      for (int mk = 0; mk < 4; ++mk)
#pragma unroll
        for (int i = 0; i < 4; ++i) {
          st[mk][n][i] = __expf(st[mk][n][i] - mx);
          sum += st[mk][n][i];
        }
      sum += __shfl_xor(sum, 16, 64);
      sum += __shfl_xor(sum, 32, 64);
      rinv[n] = 1.0f / sum;   // folded into O^T rescale
    }
  }

  // ---- build ALL P B-frags first (st dies), then PV: O^T = V^T @ P^T ----
  bf16x8 pB[2][2];
#pragma unroll
  for (int kk = 0; kk < 2; ++kk)
#pragma unroll
    for (int n = 0; n < 2; ++n) {
      unsigned pp[4], w[8];
#pragma unroll
      for (int i = 0; i < 4; ++i) pp[i] = pk2(st[2*kk][n][i], st[2*kk+1][n][i]);
#pragma unroll
      for (int j = 0; j < 8; ++j) w[j] = __shfl(pp[j & 3], (j < 4) ? sA : sB, 64);
      uintx4 u;
#pragma unroll
      for (int t = 0; t < 4; ++t) u[t] = __builtin_amdgcn_perm(w[2*t+1], w[2*t], selp);
      pB[kk][n] = __builtin_bit_cast(bf16x8, u);
    }
  floatx4 ot[2][2] = {};
#pragma unroll
  for (int kk = 0; kk < 2; ++kk) {
    bf16x8 vf[2];
#pragma unroll
    for (int mo = 0; mo < 2; ++mo) {
      int chG = h*32 + mo*16 + lr;
      vf[mo] = frag_bf(vT + SWZ(chG*64 + kk*32 + lg*8, chG));
    }
#pragma unroll
    for (int mo = 0; mo < 2; ++mo)
#pragma unroll
      for (int n = 0; n < 2; ++n)
        ot[mo][n] = MFMA(vf[mo], pB[kk][n], ot[mo][n]);
  }

  // ---- rescale by 1/sum, write outp[tok][ch] (overlays cb) ----
#pragma unroll
  for (int mo = 0; mo < 2; ++mo)
#pragma unroll
    for (int n = 0; n < 2; ++n) {
      int tok = (2*s + n)*16 + lr;
      short4v t4;
#pragma unroll
      for (int i = 0; i < 4; ++i) t4[i] = bfbits(ot[mo][n][i] * rinv[n]);
      *(short4v*)(outp + SWZ(tok*128 + h*32 + mo*16 + lg*4, tok)) = t4;
    }
  __syncthreads();  // B4: outp ready

  // ---- out = outp @ proj_w.T + proj_b ----
  {
    floatx4 ap[2][2] = {};
    for (int ks = 0; ks < 4; ++ks) {
      bf16x8 of[2], wpf[2];
#pragma unroll
      for (int m = 0; m < 2; ++m) {
        int tok = s*32 + m*16 + lr;
        of[m] = frag_bf(outp + SWZ(tok*128 + ks*32 + lg*8, tok));
      }
#pragma unroll
      for (int n = 0; n < 2; ++n)
        wpf[n] = frag_bf(wproj + (h*32 + n*16 + lr)*DIM + ks*32 + lg*8);
#pragma unroll
      for (int m = 0; m < 2; ++m)
#pragma unroll
        for (int n = 0; n < 2; ++n)
          ap[m][n] = MFMA(of[m], wpf[n], ap[m][n]);
    }
    float pb0 = proj_b[h*32 + lr], pb1 = proj_b[h*32 + 16 + lr];
    float* op = out + (size_t)b * (NT*DIM);
#pragma unroll
    for (int m = 0; m < 2; ++m)
#pragma unroll
      for (int n = 0; n < 2; ++n) {
        float pb = n ? pb1 : pb0;
#pragma unroll
        for (int i = 0; i < 4; ++i)
          op[(s*32 + m*16 + lg*4 + i)*DIM + h*32 + n*16 + lr] = ap[m][n][i] + pb;
      }
  }
}

extern "C" void kernel_launch(void* const* d_in, const int* in_sizes, int n_in,
                              void* d_out, int out_size, void* d_ws, size_t ws_size,
                              hipStream_t stream) {
  const float* x     = (const float*)d_in[0];
  const float* ctx   = (const float*)d_in[1];
  const float* mask  = (const float*)d_in[2];
  const float* q_w   = (const float*)d_in[3];
  const float* q_b   = (const float*)d_in[4];
  const float* kv_w  = (const float*)d_in[5];
  const float* v_b   = (const float*)d_in[6];
  const float* ls    = (const float*)d_in[7];
  const float* w1    = (const float*)d_in[8];
  const float* b1    = (const float*)d_in[9];
  const float* w2    = (const float*)d_in[10];
  const float* pw    = (const float*)d_in[11];
  const float* pb    = (const float*)d_in[12];
  const float* table = (const float*)d_in[13];
  const int*   idx   = (const int*)d_in[14];

  float* bias_p = (float*)d_ws;                       // 16384 f32 = 64 KB
  short* wbf    = (short*)((char*)d_ws + 65536);      // 65536 bf16 = 128 KB
  short* wq     = wbf;
  short* wkv    = wbf + 16384;
  short* wproj  = wbf + 49152;
  int B = in_sizes[0] / (NT * DIM);

  prep_kernel<<<17, 256, 0, stream>>>(table, w1, b1, w2, idx, q_w, kv_w, pw,
                                      bias_p, wbf);
  swin_ctx_attn_kernel<<<B, 512, 0, stream>>>(x, ctx, mask, wq, q_b, wkv, v_b,
                                              ls, wproj, pb, bias_p, (float*)d_out);
}